// Round 5
// baseline (12924.181 us; speedup 1.0000x reference)
//
#include <hip/hip_runtime.h>
#include <math.h>

#define DECAY 0.8f
constexpr int B_   = 16;
constexpr int NSEQ = 4096;
constexpr int D    = 64;
constexpr int C    = 4096;
constexpr int N    = B_ * NSEQ;      // 65536 rows

typedef __attribute__((ext_vector_type(8))) short bf16x8;
typedef __attribute__((ext_vector_type(4))) float f32x4;

__device__ __forceinline__ unsigned short bf16_rn(float f) {
    unsigned u = __builtin_bit_cast(unsigned, f);
    u += 0x7FFFu + ((u >> 16) & 1u);
    return (unsigned short)(u >> 16);
}
__device__ __forceinline__ float bf16_to_f(unsigned short h) {
    unsigned u = ((unsigned)h) << 16;
    return __builtin_bit_cast(float, u);
}
__device__ __forceinline__ f32x4 mfma16(bf16x8 a, bf16x8 b, f32x4 c) {
    return __builtin_amdgcn_mfma_f32_16x16x32_bf16(a, b, c, 0, 0, 0);
}

// ---------------------------------------------------------------------------
// Kernel 1: embed_n = l2norm(embed) (f32), plus bf16 hi/lo split written in
// the XOR-swizzled LDS-image layout (granule g of code row stored at
// g^(code&7)) so the assign kernel stages linearly and reads conflict-free.
// Zeroes embed_sum / bins / dirty_count.
// ---------------------------------------------------------------------------
__global__ __launch_bounds__(256) void prep_e_kernel(
    const float* __restrict__ embed,
    float* __restrict__ embed_n,
    unsigned short* __restrict__ e_hi,
    unsigned short* __restrict__ e_lo,
    float* __restrict__ embed_sum,
    float* __restrict__ bins,
    int* __restrict__ dirty_count)
{
    int code = blockIdx.x * 4 + (threadIdx.x >> 6);
    int lane = threadIdx.x & 63;
    float v = embed[code * D + lane];
    float ss = v * v;
    #pragma unroll
    for (int o = 32; o > 0; o >>= 1) ss += __shfl_xor(ss, o);
    float inv = 1.0f / fmaxf(sqrtf(ss), 1e-12f);
    float en = v * inv;
    embed_n[code * D + lane] = en;

    unsigned short hi = bf16_rn(en);
    unsigned short lo = bf16_rn(en - bf16_to_f(hi));
    int g   = lane >> 3;                               // 16B granule 0..7
    int pos = code * D + ((g ^ (code & 7)) << 3) + (lane & 7);
    e_hi[pos] = hi;
    e_lo[pos] = lo;

    embed_sum[code * D + lane] = 0.0f;
    if (lane == 0) bins[code] = 0.0f;
    if (blockIdx.x == 0 && threadIdx.x == 0) *dirty_count = 0;
}

// ---------------------------------------------------------------------------
// Kernel 2: MFMA partial argmax over a 2048-code chunk (blockIdx.y selects).
// 1024 blocks = 4 blocks/CU (vs round-4's grid-capped 2). LDS 32 KB/block.
//
// Bookkeeping uses index-in-mantissa packing: low 8 mantissa bits of each
// dist replaced by inv_pt = 255 - global_tile_id. Per element the top-2
// update is then and_or + min + 2*max (no cndmask cascade, no index regs):
//   m1' = max(m1, pv);  m2' = max(m2, min(m1, pv))   [exact second max]
// Slots are [g][r] so r is positional; lg resolved at the shuffle merge.
// Packed compare can only disagree with exact fp32 ordering when the packed
// margin <= quantum(3.7e-4)+mfma_err(6e-5) << THR=1.5e-3, and every such row
// is dirty-flagged for the exact fp32 fallback -> airtight.
// Partial (m1, idx, m2, 0) written to the row's quantize slot (float4 at
// chunk*4), consumed by merge_kernel before scatter overwrites it.
// ---------------------------------------------------------------------------
__global__ __launch_bounds__(256, 4) void assign_mfma_kernel(
    const float* __restrict__ x,
    const unsigned short* __restrict__ e_hi,
    const unsigned short* __restrict__ e_lo,
    float* __restrict__ part)               // == q_out region of d_out
{
    __shared__ unsigned short lds_hi[128 * D];   // 16 KB
    __shared__ unsigned short lds_lo[128 * D];   // 16 KB

    const int tid  = threadIdx.x;
    const int lane = tid & 63;
    const int wid  = tid >> 6;
    const int l15  = lane & 15;
    const int lg   = lane >> 4;                  // 0..3
    const int rb   = (blockIdx.x * 4 + wid) * 32;
    const int cy   = blockIdx.y;                 // code chunk 0/1

    // ---- x fragments (2 row-groups x 2 K-chunks), bf16 hi/lo split
    bf16x8 xhi[2][2], xlo[2][2];
    #pragma unroll
    for (int g = 0; g < 2; ++g) {
        #pragma unroll
        for (int c = 0; c < 2; ++c) {
            const float* p = x + (size_t)(rb + g * 16 + l15) * D + c * 32 + lg * 8;
            float4 t0 = *(const float4*)p;
            float4 t1 = *(const float4*)(p + 4);
            float e[8] = {t0.x, t0.y, t0.z, t0.w, t1.x, t1.y, t1.z, t1.w};
            bf16x8 h, l2;
            #pragma unroll
            for (int j = 0; j < 8; ++j) {
                unsigned short hh = bf16_rn(e[j]);
                h[j]  = (short)hh;
                l2[j] = (short)bf16_rn(e[j] - bf16_to_f(hh));
            }
            xhi[g][c] = h;
            xlo[g][c] = l2;
        }
    }

    // swizzled LDS read offsets; granule index = c*4+lg, s7 = l15&7
    const int s7   = l15 & 7;
    const int off0 = l15 * D + (((0 + lg) ^ s7) << 3);
    const int off1 = l15 * D + (((4 + lg) ^ s7) << 3);

    float m1[2][4], m2[2][4];
    #pragma unroll
    for (int g = 0; g < 2; ++g)
        #pragma unroll
        for (int r = 0; r < 4; ++r) { m1[g][r] = -3.4e38f; m2[g][r] = -3.4e38f; }

    for (int p = 0; p < 16; ++p) {               // 16 panels of 128 codes
        const int pp = cy * 16 + p;              // global panel id
        __syncthreads();
        {   // linear stage: 32 KB total
            const float4* gh = (const float4*)(e_hi + (size_t)pp * 128 * D);
            const float4* gl = (const float4*)(e_lo + (size_t)pp * 128 * D);
            float4* lh = (float4*)lds_hi;
            float4* ll = (float4*)lds_lo;
            #pragma unroll
            for (int i = 0; i < 4; ++i) {
                lh[i * 256 + tid] = gh[i * 256 + tid];
                ll[i * 256 + tid] = gl[i * 256 + tid];
            }
        }
        __syncthreads();

        #pragma unroll
        for (int t = 0; t < 8; ++t) {            // 8 code-tiles of 16
            bf16x8 eh0 = *(const bf16x8*)(lds_hi + t * 1024 + off0);
            bf16x8 eh1 = *(const bf16x8*)(lds_hi + t * 1024 + off1);
            bf16x8 el0 = *(const bf16x8*)(lds_lo + t * 1024 + off0);
            bf16x8 el1 = *(const bf16x8*)(lds_lo + t * 1024 + off1);
            const unsigned inv = 255u - (unsigned)(pp * 8 + t);
            #pragma unroll
            for (int g = 0; g < 2; ++g) {
                f32x4 acc = {0.f, 0.f, 0.f, 0.f};
                acc = mfma16(eh0, xhi[g][0], acc);
                acc = mfma16(eh1, xhi[g][1], acc);
                acc = mfma16(el0, xhi[g][0], acc);
                acc = mfma16(el1, xhi[g][1], acc);
                acc = mfma16(eh0, xlo[g][0], acc);
                acc = mfma16(eh1, xlo[g][1], acc);
                #pragma unroll
                for (int r = 0; r < 4; ++r) {
                    unsigned u = (__builtin_bit_cast(unsigned, acc[r]) & 0xFFFFFF00u) | inv;
                    float pv = __builtin_bit_cast(float, u);
                    float mn = fminf(m1[g][r], pv);
                    m1[g][r] = fmaxf(m1[g][r], pv);
                    m2[g][r] = fmaxf(m2[g][r], mn);
                }
            }
        }
    }

    // ---- merge 4 r-slots (exact: second = max(m2s, min of winners)), then lg
    #pragma unroll
    for (int g = 0; g < 2; ++g) {
        float a1 = m1[g][0], a2 = m2[g][0];
        int   ar = 0;
        #pragma unroll
        for (int r = 1; r < 4; ++r) {            // ascending r, strict '>'
            float v1 = m1[g][r];
            a2 = fmaxf(a2, fmaxf(m2[g][r], fminf(a1, v1)));
            bool take = v1 > a1;
            ar = take ? r : ar;
            a1 = fmaxf(a1, v1);
        }
        int pt   = 255 - (int)(__builtin_bit_cast(unsigned, a1) & 0xFFu);
        int code = pt * 16 + lg * 4 + ar;        // decode before lg-shuffle
        #pragma unroll
        for (int d = 16; d <= 32; d <<= 1) {
            float b1 = __shfl_xor(a1, d);
            float b2 = __shfl_xor(a2, d);
            int   bi = __shfl_xor(code, d);
            a2 = fmaxf(a2, fmaxf(b2, fminf(a1, b1)));
            bool take = (b1 > a1) || (b1 == a1 && bi < code);
            a1   = take ? b1 : a1;
            code = take ? bi : code;
        }
        if (lane < 16) {
            int row = rb + g * 16 + lane;
            float4 pr;
            pr.x = a1; pr.y = (float)code; pr.z = a2; pr.w = 0.0f;
            *reinterpret_cast<float4*>(part + (size_t)row * D + cy * 4) = pr;
        }
    }
}

// ---------------------------------------------------------------------------
// Kernel 3: merge the 2 chunk partials per row -> ind_out + dirty list.
// Chunk0 holds the smaller codes; strict '>' keeps chunk0 on cleared-value
// ties (positive case); all within-quantum cases land on the dirty list.
// ---------------------------------------------------------------------------
__global__ __launch_bounds__(256) void merge_kernel(
    const float* __restrict__ part,          // == q_out region
    float* __restrict__ ind_out,
    int* __restrict__ dirty_count,
    int* __restrict__ dirty_list)
{
    int row = blockIdx.x * 256 + threadIdx.x;
    float4 P0 = *reinterpret_cast<const float4*>(part + (size_t)row * D);
    float4 P1 = *reinterpret_cast<const float4*>(part + (size_t)row * D + 4);
    float a1 = P0.x; int code = (int)P0.y; float a2 = P0.z;
    float b1 = P1.x; int bi   = (int)P1.y; float b2 = P1.z;
    float m2 = fmaxf(fmaxf(a2, b2), fminf(a1, b1));
    if (b1 > a1) { a1 = b1; code = bi; }
    ind_out[row] = (float)code;
    if (a1 - m2 <= 1.5e-3f) {
        int slot = atomicAdd(dirty_count, 1);
        dirty_list[slot] = row;
    }
}

// ---------------------------------------------------------------------------
// Kernel 4: exact fp32 re-argmax for dirty rows. One block per dirty row
// (grid-stride); ascending scan + ascending block-reduce == first-max.
// ---------------------------------------------------------------------------
__global__ __launch_bounds__(256) void fallback_kernel(
    const float* __restrict__ x,
    const float* __restrict__ embed_n,
    const int* __restrict__ dirty_count,
    const int* __restrict__ dirty_list,
    float* __restrict__ ind_out)
{
    __shared__ float xs[D];
    __shared__ float bv[256];
    __shared__ int   bidx[256];
    int cnt = *dirty_count;
    for (int i = blockIdx.x; i < cnt; i += gridDim.x) {
        int row = dirty_list[i];
        __syncthreads();
        if (threadIdx.x < D) xs[threadIdx.x] = x[(size_t)row * D + threadIdx.x];
        __syncthreads();
        float best = -3.4e38f;
        int   bi   = 0;
        int   c0   = threadIdx.x * 16;
        for (int c = c0; c < c0 + 16; ++c) {
            const float4* ep = (const float4*)(embed_n + (size_t)c * D);
            const float4* xp = (const float4*)xs;
            float a0 = 0.f, a1 = 0.f, a2 = 0.f, a3 = 0.f;
            #pragma unroll
            for (int k = 0; k < D / 4; ++k) {
                float4 e = ep[k], xx = xp[k];
                a0 = fmaf(e.x, xx.x, a0);
                a1 = fmaf(e.y, xx.y, a1);
                a2 = fmaf(e.z, xx.z, a2);
                a3 = fmaf(e.w, xx.w, a3);
            }
            float dd = (a0 + a1) + (a2 + a3);
            if (dd > best) { best = dd; bi = c; }
        }
        bv[threadIdx.x]   = best;
        bidx[threadIdx.x] = bi;
        __syncthreads();
        if (threadIdx.x == 0) {
            float fb = -3.4e38f; int fi = 0;
            for (int t = 0; t < 256; ++t)
                if (bv[t] > fb) { fb = bv[t]; fi = bidx[t]; }
            ind_out[row] = (float)fi;
        }
    }
}

// ---------------------------------------------------------------------------
// Kernel 5: scatter epilogue, one WAVE per row (runs after fallback so the
// final indices feed bins/embed_sum): quantize gather (overwrites partials),
// one embed_sum atomic per lane, one bins atomic per row.
// ---------------------------------------------------------------------------
__global__ __launch_bounds__(256) void scatter_kernel(
    const float* __restrict__ x,
    const float* __restrict__ embed,
    const float* __restrict__ ind_out,
    float* __restrict__ q_out,
    float* __restrict__ embed_sum,
    float* __restrict__ bins)
{
    int wid  = threadIdx.x >> 6;
    int lane = threadIdx.x & 63;
    int row  = blockIdx.x * 4 + wid;
    int fi   = (int)ind_out[row];
    float xk = x[(size_t)row * D + lane];
    float ss = xk * xk;
    #pragma unroll
    for (int o = 32; o > 0; o >>= 1) ss += __shfl_xor(ss, o);
    float inv = 1.0f / fmaxf(sqrtf(ss), 1e-12f);
    q_out[(size_t)row * D + lane] = embed[(size_t)fi * D + lane];
    atomicAdd(&embed_sum[(size_t)fi * D + lane], xk * inv);
    if (lane == 0) atomicAdd(&bins[fi], 1.0f);
}

// ---------------------------------------------------------------------------
// Kernel 6: EMA finalize per code. One wave per code.
// ---------------------------------------------------------------------------
__global__ __launch_bounds__(256) void finalize_kernel(
    const float* __restrict__ embed,
    const float* __restrict__ cluster_size,
    const float* __restrict__ embed_n,
    const float* __restrict__ embed_sum,
    const float* __restrict__ bins,
    float* __restrict__ new_embed_out,
    float* __restrict__ new_cs_out)
{
    int code = blockIdx.x * 4 + (threadIdx.x >> 6);
    int lane = threadIdx.x & 63;
    float bsum = bins[code];
    if (lane == 0)
        new_cs_out[code] = cluster_size[code] * DECAY + bsum * (1.0f - DECAY);

    float en;
    if (bsum == 0.0f) {
        en = embed_n[code * D + lane];
    } else {
        float v = embed_sum[code * D + lane] / bsum;
        float ss = v * v;
        #pragma unroll
        for (int o = 32; o > 0; o >>= 1) ss += __shfl_xor(ss, o);
        en = v / fmaxf(sqrtf(ss), 1e-12f);
    }
    new_embed_out[code * D + lane] =
        embed[code * D + lane] * DECAY + en * (1.0f - DECAY);
}

// ---------------------------------------------------------------------------
extern "C" void kernel_launch(void* const* d_in, const int* in_sizes, int n_in,
                              void* d_out, int out_size, void* d_ws, size_t ws_size,
                              hipStream_t stream)
{
    const float* x            = (const float*)d_in[0];
    const float* embed        = (const float*)d_in[1];
    const float* cluster_size = (const float*)d_in[2];

    float* out     = (float*)d_out;
    float* q_out   = out;                          // N*D
    float* ind_out = out + (size_t)N * D;          // N
    float* ne_out  = ind_out + N;                  // C*D
    float* ncs_out = ne_out + (size_t)C * D;       // C

    char* ws = (char*)d_ws;
    float*          embed_n     = (float*)ws;                       // 1 MB
    float*          embed_sum   = (float*)(ws + (1u << 20));        // 1 MB
    float*          bins        = (float*)(ws + (2u << 20));        // 16 KB
    int*            dirty_list  = (int*)(ws + (2u << 20) + 65536);  // 256 KB
    int*            dirty_count = (int*)(ws + (2u << 20) + 65536 + 262144);
    unsigned short* e_hi        = (unsigned short*)(ws + 3 * (1u << 20));  // 512 KB
    unsigned short* e_lo        = (unsigned short*)(ws + 3 * (1u << 20) + 524288);

    prep_e_kernel<<<C / 4, 256, 0, stream>>>(embed, embed_n, e_hi, e_lo,
                                             embed_sum, bins, dirty_count);
    assign_mfma_kernel<<<dim3(N / 128, 2), 256, 0, stream>>>(x, e_hi, e_lo,
                                                             q_out);
    merge_kernel<<<N / 256, 256, 0, stream>>>(q_out, ind_out,
                                              dirty_count, dirty_list);
    fallback_kernel<<<256, 256, 0, stream>>>(x, embed_n, dirty_count,
                                             dirty_list, ind_out);
    scatter_kernel<<<N / 4, 256, 0, stream>>>(x, embed, ind_out, q_out,
                                              embed_sum, bins);
    finalize_kernel<<<C / 4, 256, 0, stream>>>(embed, cluster_size, embed_n,
                                               embed_sum, bins, ne_out, ncs_out);
}

// Round 6
// 246.061 us; speedup vs baseline: 52.5243x; 52.5243x over previous
//
#include <hip/hip_runtime.h>
#include <math.h>

#define DECAY 0.8f
constexpr int B_   = 16;
constexpr int NSEQ = 4096;
constexpr int D    = 64;
constexpr int C    = 4096;
constexpr int N    = B_ * NSEQ;      // 65536 rows

typedef __attribute__((ext_vector_type(8))) short bf16x8;
typedef __attribute__((ext_vector_type(4))) float f32x4;

__device__ __forceinline__ unsigned short bf16_rn(float f) {
    unsigned u = __builtin_bit_cast(unsigned, f);
    u += 0x7FFFu + ((u >> 16) & 1u);
    return (unsigned short)(u >> 16);
}
__device__ __forceinline__ float bf16_to_f(unsigned short h) {
    unsigned u = ((unsigned)h) << 16;
    return __builtin_bit_cast(float, u);
}
__device__ __forceinline__ f32x4 mfma16(bf16x8 a, bf16x8 b, f32x4 c) {
    return __builtin_amdgcn_mfma_f32_16x16x32_bf16(a, b, c, 0, 0, 0);
}

// ---------------------------------------------------------------------------
// Kernel 1: embed_n = l2norm(embed) (f32), plus bf16 hi/lo split written in
// the XOR-swizzled LDS-image layout (granule g of code row stored at
// g^(code&7)) so the assign kernel stages linearly and reads conflict-free.
// Zeroes embed_sum / bins / dirty_count.
// ---------------------------------------------------------------------------
__global__ __launch_bounds__(256) void prep_e_kernel(
    const float* __restrict__ embed,
    float* __restrict__ embed_n,
    unsigned short* __restrict__ e_hi,
    unsigned short* __restrict__ e_lo,
    float* __restrict__ embed_sum,
    float* __restrict__ bins,
    int* __restrict__ dirty_count)
{
    int code = blockIdx.x * 4 + (threadIdx.x >> 6);
    int lane = threadIdx.x & 63;
    float v = embed[code * D + lane];
    float ss = v * v;
    #pragma unroll
    for (int o = 32; o > 0; o >>= 1) ss += __shfl_xor(ss, o);
    float inv = 1.0f / fmaxf(sqrtf(ss), 1e-12f);
    float en = v * inv;
    embed_n[code * D + lane] = en;

    unsigned short hi = bf16_rn(en);
    unsigned short lo = bf16_rn(en - bf16_to_f(hi));
    int g   = lane >> 3;                               // 16B granule 0..7
    int pos = code * D + ((g ^ (code & 7)) << 3) + (lane & 7);
    e_hi[pos] = hi;
    e_lo[pos] = lo;

    embed_sum[code * D + lane] = 0.0f;
    if (lane == 0) bins[code] = 0.0f;
    if (blockIdx.x == 0 && threadIdx.x == 0) *dirty_count = 0;
}

// ---------------------------------------------------------------------------
// Kernel 2: MFMA partial argmax over a 2048-code chunk (blockIdx.y selects).
// 1024 blocks = 4 blocks/CU. LDS 32 KB/block. EXACT round-4 top-2-with-index
// bookkeeping (cndmask form, hardware-verified small dirty set) — the round-5
// packed-mantissa variant flagged ~every row dirty and is abandoned.
// dist = e_hi·x_hi + e_lo·x_hi + e_hi·x_lo (bf16 split, fp32 accum;
// |err| <= ~1e-4 worst case, typ ~1.5e-5).
// Partial (m1, idx, m2, 0) -> the row's quantize slot (float4 at chunk*4),
// consumed by merge_kernel before scatter overwrites the slot.
// ---------------------------------------------------------------------------
__global__ __launch_bounds__(256) void assign_mfma_kernel(
    const float* __restrict__ x,
    const unsigned short* __restrict__ e_hi,
    const unsigned short* __restrict__ e_lo,
    float* __restrict__ part)               // == q_out region of d_out
{
    __shared__ unsigned short lds_hi[128 * D];   // 16 KB
    __shared__ unsigned short lds_lo[128 * D];   // 16 KB

    const int tid  = threadIdx.x;
    const int lane = tid & 63;
    const int wid  = tid >> 6;
    const int l15  = lane & 15;
    const int lg   = lane >> 4;                  // 0..3
    const int rb   = (blockIdx.x * 4 + wid) * 32;
    const int cy   = blockIdx.y;                 // code chunk 0/1

    // ---- x fragments (2 row-groups x 2 K-chunks), bf16 hi/lo split
    bf16x8 xhi[2][2], xlo[2][2];
    #pragma unroll
    for (int g = 0; g < 2; ++g) {
        #pragma unroll
        for (int c = 0; c < 2; ++c) {
            const float* p = x + (size_t)(rb + g * 16 + l15) * D + c * 32 + lg * 8;
            float4 t0 = *(const float4*)p;
            float4 t1 = *(const float4*)(p + 4);
            float e[8] = {t0.x, t0.y, t0.z, t0.w, t1.x, t1.y, t1.z, t1.w};
            bf16x8 h, l2;
            #pragma unroll
            for (int j = 0; j < 8; ++j) {
                unsigned short hh = bf16_rn(e[j]);
                h[j]  = (short)hh;
                l2[j] = (short)bf16_rn(e[j] - bf16_to_f(hh));
            }
            xhi[g][c] = h;
            xlo[g][c] = l2;
        }
    }

    // swizzled LDS read offsets; granule index = c*4+lg, s7 = l15&7
    const int s7   = l15 & 7;
    const int off0 = l15 * D + (((0 + lg) ^ s7) << 3);
    const int off1 = l15 * D + (((4 + lg) ^ s7) << 3);

    float m1[2][4], m2[2][4];
    int   i1[2][4];
    #pragma unroll
    for (int g = 0; g < 2; ++g)
        #pragma unroll
        for (int r = 0; r < 4; ++r) {
            m1[g][r] = -3.4e38f; m2[g][r] = -3.4e38f; i1[g][r] = 0;
        }

    for (int p = 0; p < 16; ++p) {               // 16 panels of 128 codes
        const int pp = cy * 16 + p;              // global panel id
        __syncthreads();
        {   // linear stage: 32 KB total
            const float4* gh = (const float4*)(e_hi + (size_t)pp * 128 * D);
            const float4* gl = (const float4*)(e_lo + (size_t)pp * 128 * D);
            float4* lh = (float4*)lds_hi;
            float4* ll = (float4*)lds_lo;
            #pragma unroll
            for (int i = 0; i < 4; ++i) {
                lh[i * 256 + tid] = gh[i * 256 + tid];
                ll[i * 256 + tid] = gl[i * 256 + tid];
            }
        }
        __syncthreads();

        #pragma unroll
        for (int t = 0; t < 8; ++t) {            // 8 code-tiles of 16
            bf16x8 eh0 = *(const bf16x8*)(lds_hi + t * 1024 + off0);
            bf16x8 eh1 = *(const bf16x8*)(lds_hi + t * 1024 + off1);
            bf16x8 el0 = *(const bf16x8*)(lds_lo + t * 1024 + off0);
            bf16x8 el1 = *(const bf16x8*)(lds_lo + t * 1024 + off1);
            const int cbase = (pp * 8 + t) * 16 + lg * 4;
            #pragma unroll
            for (int g = 0; g < 2; ++g) {
                f32x4 acc = {0.f, 0.f, 0.f, 0.f};
                acc = mfma16(eh0, xhi[g][0], acc);
                acc = mfma16(eh1, xhi[g][1], acc);
                acc = mfma16(el0, xhi[g][0], acc);
                acc = mfma16(el1, xhi[g][1], acc);
                acc = mfma16(eh0, xlo[g][0], acc);
                acc = mfma16(eh1, xlo[g][1], acc);
                #pragma unroll
                for (int r = 0; r < 4; ++r) {
                    float v  = acc[r];
                    bool  gt = v > m1[g][r];
                    float mx = fmaxf(m2[g][r], v);
                    m2[g][r] = gt ? m1[g][r] : mx;
                    i1[g][r] = gt ? (cbase + r) : i1[g][r];
                    m1[g][r] = gt ? v : m1[g][r];
                }
            }
        }
    }

    // ---- merge 4 r-slots (exact second-max), then lg groups via shuffle ----
    #pragma unroll
    for (int g = 0; g < 2; ++g) {
        float a1 = m1[g][0], a2 = m2[g][0];
        int   ai = i1[g][0];
        #pragma unroll
        for (int r = 1; r < 4; ++r) {            // ascending r = ascending code
            float b1 = m1[g][r], b2 = m2[g][r];
            int   bi = i1[g][r];
            float nm2 = fmaxf(fminf(a1, b1), fmaxf(a2, b2));
            bool  take = (b1 > a1);
            a1 = take ? b1 : a1;
            ai = take ? bi : ai;
            a2 = nm2;
        }
        #pragma unroll
        for (int d = 16; d <= 32; d <<= 1) {
            float b1 = __shfl_xor(a1, d);
            float b2 = __shfl_xor(a2, d);
            int   bi = __shfl_xor(ai, d);
            float nm2 = fmaxf(fminf(a1, b1), fmaxf(a2, b2));
            bool  take = (b1 > a1) || (b1 == a1 && bi < ai);
            a1 = take ? b1 : a1;
            ai = take ? bi : ai;
            a2 = nm2;
        }
        if (lane < 16) {
            int row = rb + g * 16 + lane;
            float4 pr;
            pr.x = a1; pr.y = (float)ai; pr.z = a2; pr.w = 0.0f;
            *reinterpret_cast<float4*>(part + (size_t)row * D + cy * 4) = pr;
        }
    }
}

// ---------------------------------------------------------------------------
// Kernel 3: merge the 2 chunk partials per row -> ind_out + dirty list.
// Chunk0 holds the smaller codes; strict '>' keeps chunk0 on exact ties.
// THR = 1.2e-3 (>> 2x worst-case mfma-split error ~2e-4) -> airtight; any
// row whose exact ordering could differ lands on the dirty list.
// ---------------------------------------------------------------------------
__global__ __launch_bounds__(256) void merge_kernel(
    const float* __restrict__ part,          // == q_out region
    float* __restrict__ ind_out,
    int* __restrict__ dirty_count,
    int* __restrict__ dirty_list)
{
    int row = blockIdx.x * 256 + threadIdx.x;
    float4 P0 = *reinterpret_cast<const float4*>(part + (size_t)row * D);
    float4 P1 = *reinterpret_cast<const float4*>(part + (size_t)row * D + 4);
    float a1 = P0.x; int code = (int)P0.y; float a2 = P0.z;
    float b1 = P1.x; int bi   = (int)P1.y; float b2 = P1.z;
    float m2 = fmaxf(fmaxf(a2, b2), fminf(a1, b1));
    if (b1 > a1) { a1 = b1; code = bi; }
    ind_out[row] = (float)code;
    if (a1 - m2 <= 1.2e-3f) {
        int slot = atomicAdd(dirty_count, 1);
        dirty_list[slot] = row;
    }
}

// ---------------------------------------------------------------------------
// Kernel 4: exact fp32 re-argmax for dirty rows. 1024 blocks, one block per
// dirty row (grid-stride). Thread t scans codes [16t,16t+16) ascending;
// LDS tree reduce with explicit lower-index tie-break == reference argmax.
// ---------------------------------------------------------------------------
__global__ __launch_bounds__(256) void fallback_kernel(
    const float* __restrict__ x,
    const float* __restrict__ embed_n,
    const int* __restrict__ dirty_count,
    const int* __restrict__ dirty_list,
    float* __restrict__ ind_out)
{
    __shared__ float xs[D];
    __shared__ float bv[256];
    __shared__ int   bidx[256];
    int cnt = *dirty_count;
    for (int i = blockIdx.x; i < cnt; i += gridDim.x) {
        int row = dirty_list[i];
        __syncthreads();
        if (threadIdx.x < D) xs[threadIdx.x] = x[(size_t)row * D + threadIdx.x];
        __syncthreads();
        float best = -3.4e38f;
        int   bi   = 0;
        int   c0   = threadIdx.x * 16;
        for (int c = c0; c < c0 + 16; ++c) {
            const float4* ep = (const float4*)(embed_n + (size_t)c * D);
            const float4* xp = (const float4*)xs;
            float a0 = 0.f, a1 = 0.f, a2 = 0.f, a3 = 0.f;
            #pragma unroll
            for (int k = 0; k < D / 4; ++k) {
                float4 e = ep[k], xx = xp[k];
                a0 = fmaf(e.x, xx.x, a0);
                a1 = fmaf(e.y, xx.y, a1);
                a2 = fmaf(e.z, xx.z, a2);
                a3 = fmaf(e.w, xx.w, a3);
            }
            float dd = (a0 + a1) + (a2 + a3);
            if (dd > best) { best = dd; bi = c; }
        }
        bv[threadIdx.x]   = best;
        bidx[threadIdx.x] = bi;
        __syncthreads();
        #pragma unroll
        for (int s = 128; s > 0; s >>= 1) {
            if (threadIdx.x < s) {
                float v2 = bv[threadIdx.x + s];
                int   i2 = bidx[threadIdx.x + s];
                if (v2 > bv[threadIdx.x] ||
                    (v2 == bv[threadIdx.x] && i2 < bidx[threadIdx.x])) {
                    bv[threadIdx.x]   = v2;
                    bidx[threadIdx.x] = i2;
                }
            }
            __syncthreads();
        }
        if (threadIdx.x == 0) ind_out[row] = (float)bidx[0];
    }
}

// ---------------------------------------------------------------------------
// Kernel 5: scatter epilogue, one WAVE per row (after fallback so the final
// indices feed bins/embed_sum): quantize gather (overwrites partials), one
// embed_sum atomic per lane, one bins atomic per row.
// ---------------------------------------------------------------------------
__global__ __launch_bounds__(256) void scatter_kernel(
    const float* __restrict__ x,
    const float* __restrict__ embed,
    const float* __restrict__ ind_out,
    float* __restrict__ q_out,
    float* __restrict__ embed_sum,
    float* __restrict__ bins)
{
    int wid  = threadIdx.x >> 6;
    int lane = threadIdx.x & 63;
    int row  = blockIdx.x * 4 + wid;
    int fi   = (int)ind_out[row];
    float xk = x[(size_t)row * D + lane];
    float ss = xk * xk;
    #pragma unroll
    for (int o = 32; o > 0; o >>= 1) ss += __shfl_xor(ss, o);
    float inv = 1.0f / fmaxf(sqrtf(ss), 1e-12f);
    q_out[(size_t)row * D + lane] = embed[(size_t)fi * D + lane];
    atomicAdd(&embed_sum[(size_t)fi * D + lane], xk * inv);
    if (lane == 0) atomicAdd(&bins[fi], 1.0f);
}

// ---------------------------------------------------------------------------
// Kernel 6: EMA finalize per code. One wave per code.
// ---------------------------------------------------------------------------
__global__ __launch_bounds__(256) void finalize_kernel(
    const float* __restrict__ embed,
    const float* __restrict__ cluster_size,
    const float* __restrict__ embed_n,
    const float* __restrict__ embed_sum,
    const float* __restrict__ bins,
    float* __restrict__ new_embed_out,
    float* __restrict__ new_cs_out)
{
    int code = blockIdx.x * 4 + (threadIdx.x >> 6);
    int lane = threadIdx.x & 63;
    float bsum = bins[code];
    if (lane == 0)
        new_cs_out[code] = cluster_size[code] * DECAY + bsum * (1.0f - DECAY);

    float en;
    if (bsum == 0.0f) {
        en = embed_n[code * D + lane];
    } else {
        float v = embed_sum[code * D + lane] / bsum;
        float ss = v * v;
        #pragma unroll
        for (int o = 32; o > 0; o >>= 1) ss += __shfl_xor(ss, o);
        en = v / fmaxf(sqrtf(ss), 1e-12f);
    }
    new_embed_out[code * D + lane] =
        embed[code * D + lane] * DECAY + en * (1.0f - DECAY);
}

// ---------------------------------------------------------------------------
extern "C" void kernel_launch(void* const* d_in, const int* in_sizes, int n_in,
                              void* d_out, int out_size, void* d_ws, size_t ws_size,
                              hipStream_t stream)
{
    const float* x            = (const float*)d_in[0];
    const float* embed        = (const float*)d_in[1];
    const float* cluster_size = (const float*)d_in[2];

    float* out     = (float*)d_out;
    float* q_out   = out;                          // N*D
    float* ind_out = out + (size_t)N * D;          // N
    float* ne_out  = ind_out + N;                  // C*D
    float* ncs_out = ne_out + (size_t)C * D;       // C

    char* ws = (char*)d_ws;
    float*          embed_n     = (float*)ws;                       // 1 MB
    float*          embed_sum   = (float*)(ws + (1u << 20));        // 1 MB
    float*          bins        = (float*)(ws + (2u << 20));        // 16 KB
    int*            dirty_list  = (int*)(ws + (2u << 20) + 65536);  // 256 KB
    int*            dirty_count = (int*)(ws + (2u << 20) + 65536 + 262144);
    unsigned short* e_hi        = (unsigned short*)(ws + 3 * (1u << 20));  // 512 KB
    unsigned short* e_lo        = (unsigned short*)(ws + 3 * (1u << 20) + 524288);

    prep_e_kernel<<<C / 4, 256, 0, stream>>>(embed, embed_n, e_hi, e_lo,
                                             embed_sum, bins, dirty_count);
    assign_mfma_kernel<<<dim3(N / 128, 2), 256, 0, stream>>>(x, e_hi, e_lo,
                                                             q_out);
    merge_kernel<<<N / 256, 256, 0, stream>>>(q_out, ind_out,
                                              dirty_count, dirty_list);
    fallback_kernel<<<1024, 256, 0, stream>>>(x, embed_n, dirty_count,
                                              dirty_list, ind_out);
    scatter_kernel<<<N / 4, 256, 0, stream>>>(x, embed, ind_out, q_out,
                                              embed_sum, bins);
    finalize_kernel<<<C / 4, 256, 0, stream>>>(embed, cluster_size, embed_n,
                                               embed_sum, bins, ne_out, ncs_out);
}

// Round 7
// 241.922 us; speedup vs baseline: 53.4230x; 1.0171x over previous
//
#include <hip/hip_runtime.h>
#include <math.h>

#define DECAY 0.8f
constexpr int B_   = 16;
constexpr int NSEQ = 4096;
constexpr int D    = 64;
constexpr int C    = 4096;
constexpr int N    = B_ * NSEQ;      // 65536 rows

typedef __attribute__((ext_vector_type(8))) short bf16x8;
typedef __attribute__((ext_vector_type(4))) float f32x4;

__device__ __forceinline__ unsigned short bf16_rn(float f) {
    unsigned u = __builtin_bit_cast(unsigned, f);
    u += 0x7FFFu + ((u >> 16) & 1u);
    return (unsigned short)(u >> 16);
}
__device__ __forceinline__ float bf16_to_f(unsigned short h) {
    unsigned u = ((unsigned)h) << 16;
    return __builtin_bit_cast(float, u);
}
__device__ __forceinline__ f32x4 mfma16(bf16x8 a, bf16x8 b, f32x4 c) {
    return __builtin_amdgcn_mfma_f32_16x16x32_bf16(a, b, c, 0, 0, 0);
}

// ---------------------------------------------------------------------------
// Kernel 1: embed_n = l2norm(embed) (f32), plus bf16 hi/lo split written in
// the XOR-swizzled LDS-image layout (granule g of code row stored at
// g^(code&7)) so the assign kernel stages linearly and reads conflict-free.
// Zeroes embed_sum / bins / dirty_count.
// ---------------------------------------------------------------------------
__global__ __launch_bounds__(256) void prep_e_kernel(
    const float* __restrict__ embed,
    float* __restrict__ embed_n,
    unsigned short* __restrict__ e_hi,
    unsigned short* __restrict__ e_lo,
    float* __restrict__ embed_sum,
    float* __restrict__ bins,
    int* __restrict__ dirty_count)
{
    int code = blockIdx.x * 4 + (threadIdx.x >> 6);
    int lane = threadIdx.x & 63;
    float v = embed[code * D + lane];
    float ss = v * v;
    #pragma unroll
    for (int o = 32; o > 0; o >>= 1) ss += __shfl_xor(ss, o);
    float inv = 1.0f / fmaxf(sqrtf(ss), 1e-12f);
    float en = v * inv;
    embed_n[code * D + lane] = en;

    unsigned short hi = bf16_rn(en);
    unsigned short lo = bf16_rn(en - bf16_to_f(hi));
    int g   = lane >> 3;                               // 16B granule 0..7
    int pos = code * D + ((g ^ (code & 7)) << 3) + (lane & 7);
    e_hi[pos] = hi;
    e_lo[pos] = lo;

    embed_sum[code * D + lane] = 0.0f;
    if (lane == 0) bins[code] = 0.0f;
    if (blockIdx.x == 0 && threadIdx.x == 0) *dirty_count = 0;
}

// ---------------------------------------------------------------------------
// Kernel 2: MFMA partial argmax over a 2048-code chunk (blockIdx.y selects).
// 1024 blocks = 4 blocks/CU. LDS 32 KB/block.
// NO min-occupancy launch bound: round-6's (256,4) squeezed VGPR to 52
// (natural ~88) and bloated VALU ~4-5x vs hand count. Grid supplies
// 4 blocks/CU; VGPR ~90 still allows 4 waves/SIMD.
// Exact round-4 top-2 bookkeeping; i1 now stores the wave-uniform tile id pt
// (SGPR-source cndmask); code decoded as pt*16 + lg*4 + r at merge time.
// Exact cross-slot ties are resolved by the dirty->fallback path.
// Partial (m1, idx, m2, 0) -> the row's quantize slot (float4 at chunk*4).
// ---------------------------------------------------------------------------
__global__ __launch_bounds__(256) void assign_mfma_kernel(
    const float* __restrict__ x,
    const unsigned short* __restrict__ e_hi,
    const unsigned short* __restrict__ e_lo,
    float* __restrict__ part)               // == q_out region of d_out
{
    __shared__ unsigned short lds_hi[128 * D];   // 16 KB
    __shared__ unsigned short lds_lo[128 * D];   // 16 KB

    const int tid  = threadIdx.x;
    const int lane = tid & 63;
    const int wid  = tid >> 6;
    const int l15  = lane & 15;
    const int lg   = lane >> 4;                  // 0..3
    const int rb   = (blockIdx.x * 4 + wid) * 32;
    const int cy   = blockIdx.y;                 // code chunk 0/1

    // ---- x fragments (2 row-groups x 2 K-chunks), bf16 hi/lo split
    bf16x8 xhi[2][2], xlo[2][2];
    #pragma unroll
    for (int g = 0; g < 2; ++g) {
        #pragma unroll
        for (int c = 0; c < 2; ++c) {
            const float* p = x + (size_t)(rb + g * 16 + l15) * D + c * 32 + lg * 8;
            float4 t0 = *(const float4*)p;
            float4 t1 = *(const float4*)(p + 4);
            float e[8] = {t0.x, t0.y, t0.z, t0.w, t1.x, t1.y, t1.z, t1.w};
            bf16x8 h, l2;
            #pragma unroll
            for (int j = 0; j < 8; ++j) {
                unsigned short hh = bf16_rn(e[j]);
                h[j]  = (short)hh;
                l2[j] = (short)bf16_rn(e[j] - bf16_to_f(hh));
            }
            xhi[g][c] = h;
            xlo[g][c] = l2;
        }
    }

    // swizzled LDS read offsets; granule index = c*4+lg, s7 = l15&7
    const int s7   = l15 & 7;
    const int off0 = l15 * D + (((0 + lg) ^ s7) << 3);
    const int off1 = l15 * D + (((4 + lg) ^ s7) << 3);

    float m1[2][4], m2[2][4];
    int   i1[2][4];
    #pragma unroll
    for (int g = 0; g < 2; ++g)
        #pragma unroll
        for (int r = 0; r < 4; ++r) {
            m1[g][r] = -3.4e38f; m2[g][r] = -3.4e38f; i1[g][r] = 0;
        }

    for (int p = 0; p < 16; ++p) {               // 16 panels of 128 codes
        const int pp = cy * 16 + p;              // global panel id
        __syncthreads();
        {   // linear stage: 32 KB total
            const float4* gh = (const float4*)(e_hi + (size_t)pp * 128 * D);
            const float4* gl = (const float4*)(e_lo + (size_t)pp * 128 * D);
            float4* lh = (float4*)lds_hi;
            float4* ll = (float4*)lds_lo;
            #pragma unroll
            for (int i = 0; i < 4; ++i) {
                lh[i * 256 + tid] = gh[i * 256 + tid];
                ll[i * 256 + tid] = gl[i * 256 + tid];
            }
        }
        __syncthreads();

        #pragma unroll
        for (int t = 0; t < 8; ++t) {            // 8 code-tiles of 16
            bf16x8 eh0 = *(const bf16x8*)(lds_hi + t * 1024 + off0);
            bf16x8 eh1 = *(const bf16x8*)(lds_hi + t * 1024 + off1);
            bf16x8 el0 = *(const bf16x8*)(lds_lo + t * 1024 + off0);
            bf16x8 el1 = *(const bf16x8*)(lds_lo + t * 1024 + off1);
            const int pt = pp * 8 + t;           // wave-uniform tile id
            #pragma unroll
            for (int g = 0; g < 2; ++g) {
                f32x4 acc = {0.f, 0.f, 0.f, 0.f};
                acc = mfma16(eh0, xhi[g][0], acc);
                acc = mfma16(eh1, xhi[g][1], acc);
                acc = mfma16(el0, xhi[g][0], acc);
                acc = mfma16(el1, xhi[g][1], acc);
                acc = mfma16(eh0, xlo[g][0], acc);
                acc = mfma16(eh1, xlo[g][1], acc);
                #pragma unroll
                for (int r = 0; r < 4; ++r) {
                    float v  = acc[r];
                    bool  gt = v > m1[g][r];
                    float mx = fmaxf(m2[g][r], v);
                    m2[g][r] = gt ? m1[g][r] : mx;
                    i1[g][r] = gt ? pt : i1[g][r];   // scalar-source cndmask
                    m1[g][r] = gt ? v : m1[g][r];
                }
            }
        }
    }

    // ---- merge 4 r-slots (exact second-max), then lg groups via shuffle ----
    #pragma unroll
    for (int g = 0; g < 2; ++g) {
        float a1 = m1[g][0], a2 = m2[g][0];
        int   ai = i1[g][0] * 16 + lg * 4;       // decode slot 0
        #pragma unroll
        for (int r = 1; r < 4; ++r) {
            float b1 = m1[g][r], b2 = m2[g][r];
            int   bi = i1[g][r] * 16 + lg * 4 + r;
            float nm2 = fmaxf(fminf(a1, b1), fmaxf(a2, b2));
            bool  take = (b1 > a1);              // exact tie -> dirty path
            a1 = take ? b1 : a1;
            ai = take ? bi : ai;
            a2 = nm2;
        }
        #pragma unroll
        for (int d = 16; d <= 32; d <<= 1) {
            float b1 = __shfl_xor(a1, d);
            float b2 = __shfl_xor(a2, d);
            int   bi = __shfl_xor(ai, d);
            float nm2 = fmaxf(fminf(a1, b1), fmaxf(a2, b2));
            bool  take = (b1 > a1) || (b1 == a1 && bi < ai);
            a1 = take ? b1 : a1;
            ai = take ? bi : ai;
            a2 = nm2;
        }
        if (lane < 16) {
            int row = rb + g * 16 + lane;
            float4 pr;
            pr.x = a1; pr.y = (float)ai; pr.z = a2; pr.w = 0.0f;
            *reinterpret_cast<float4*>(part + (size_t)row * D + cy * 4) = pr;
        }
    }
}

// ---------------------------------------------------------------------------
// Kernel 3: fused merge + scatter, one WAVE per row. All lanes read the two
// chunk partials (broadcast loads), resolve the winner, and either (clean)
// write ind + gather q + do the EMA atomics, or (dirty) defer the row to the
// fallback. THR = 1.2e-3 as in round 6 (proven small dirty set, airtight
// vs the <=2e-4 split error).
// ---------------------------------------------------------------------------
__global__ __launch_bounds__(256) void merge_scatter_kernel(
    const float* __restrict__ x,
    const float* __restrict__ embed,
    float* __restrict__ q_out,               // holds partials on entry
    float* __restrict__ ind_out,
    float* __restrict__ embed_sum,
    float* __restrict__ bins,
    int* __restrict__ dirty_count,
    int* __restrict__ dirty_list)
{
    int wid  = threadIdx.x >> 6;
    int lane = threadIdx.x & 63;
    int row  = blockIdx.x * 4 + wid;

    const float4 P0 = *reinterpret_cast<const float4*>(q_out + (size_t)row * D);
    const float4 P1 = *reinterpret_cast<const float4*>(q_out + (size_t)row * D + 4);
    float a1 = P0.x; int code = (int)P0.y; float a2 = P0.z;
    float b1 = P1.x; int bi   = (int)P1.y; float b2 = P1.z;
    float m2 = fmaxf(fmaxf(a2, b2), fminf(a1, b1));
    if (b1 > a1) { a1 = b1; code = bi; }
    bool dirty = (a1 - m2 <= 1.2e-3f);       // wave-uniform

    if (dirty) {
        if (lane == 0) {
            int slot = atomicAdd(dirty_count, 1);
            dirty_list[slot] = row;
        }
        return;
    }

    float xk = x[(size_t)row * D + lane];
    float ss = xk * xk;
    #pragma unroll
    for (int o = 32; o > 0; o >>= 1) ss += __shfl_xor(ss, o);
    float inv = 1.0f / fmaxf(sqrtf(ss), 1e-12f);

    if (lane == 0) {
        ind_out[row] = (float)code;
        atomicAdd(&bins[code], 1.0f);
    }
    q_out[(size_t)row * D + lane] = embed[(size_t)code * D + lane];
    atomicAdd(&embed_sum[(size_t)code * D + lane], xk * inv);
}

// ---------------------------------------------------------------------------
// Kernel 4: exact fp32 re-argmax for dirty rows + their deferred scatter.
// 1024 blocks, one block per dirty row (grid-stride). Thread t scans codes
// [16t,16t+16) ascending; LDS tree reduce with lower-index tie-break ==
// reference argmax. Wave 0 then does ind/q/atomics for the row.
// ---------------------------------------------------------------------------
__global__ __launch_bounds__(256) void fallback_kernel(
    const float* __restrict__ x,
    const float* __restrict__ embed,
    const float* __restrict__ embed_n,
    const int* __restrict__ dirty_count,
    const int* __restrict__ dirty_list,
    float* __restrict__ ind_out,
    float* __restrict__ q_out,
    float* __restrict__ embed_sum,
    float* __restrict__ bins)
{
    __shared__ float xs[D];
    __shared__ float bv[256];
    __shared__ int   bidx[256];
    int cnt = *dirty_count;
    for (int i = blockIdx.x; i < cnt; i += gridDim.x) {
        int row = dirty_list[i];
        __syncthreads();
        if (threadIdx.x < D) xs[threadIdx.x] = x[(size_t)row * D + threadIdx.x];
        __syncthreads();
        float best = -3.4e38f;
        int   bi   = 0;
        int   c0   = threadIdx.x * 16;
        for (int c = c0; c < c0 + 16; ++c) {
            const float4* ep = (const float4*)(embed_n + (size_t)c * D);
            const float4* xp = (const float4*)xs;
            float a0 = 0.f, a1 = 0.f, a2 = 0.f, a3 = 0.f;
            #pragma unroll
            for (int k = 0; k < D / 4; ++k) {
                float4 e = ep[k], xx = xp[k];
                a0 = fmaf(e.x, xx.x, a0);
                a1 = fmaf(e.y, xx.y, a1);
                a2 = fmaf(e.z, xx.z, a2);
                a3 = fmaf(e.w, xx.w, a3);
            }
            float dd = (a0 + a1) + (a2 + a3);
            if (dd > best) { best = dd; bi = c; }
        }
        bv[threadIdx.x]   = best;
        bidx[threadIdx.x] = bi;
        __syncthreads();
        #pragma unroll
        for (int s = 128; s > 0; s >>= 1) {
            if (threadIdx.x < s) {
                float v2 = bv[threadIdx.x + s];
                int   i2 = bidx[threadIdx.x + s];
                if (v2 > bv[threadIdx.x] ||
                    (v2 == bv[threadIdx.x] && i2 < bidx[threadIdx.x])) {
                    bv[threadIdx.x]   = v2;
                    bidx[threadIdx.x] = i2;
                }
            }
            __syncthreads();
        }
        int fi = bidx[0];
        if (threadIdx.x == 0) {
            ind_out[row] = (float)fi;
            atomicAdd(&bins[fi], 1.0f);
        }
        if (threadIdx.x < 64) {
            float xk = xs[threadIdx.x];
            float ss = xk * xk;
            #pragma unroll
            for (int o = 32; o > 0; o >>= 1) ss += __shfl_xor(ss, o);
            float inv = 1.0f / fmaxf(sqrtf(ss), 1e-12f);
            q_out[(size_t)row * D + threadIdx.x] =
                embed[(size_t)fi * D + threadIdx.x];
            atomicAdd(&embed_sum[(size_t)fi * D + threadIdx.x], xk * inv);
        }
        __syncthreads();
    }
}

// ---------------------------------------------------------------------------
// Kernel 5: EMA finalize per code. One wave per code.
// ---------------------------------------------------------------------------
__global__ __launch_bounds__(256) void finalize_kernel(
    const float* __restrict__ embed,
    const float* __restrict__ cluster_size,
    const float* __restrict__ embed_n,
    const float* __restrict__ embed_sum,
    const float* __restrict__ bins,
    float* __restrict__ new_embed_out,
    float* __restrict__ new_cs_out)
{
    int code = blockIdx.x * 4 + (threadIdx.x >> 6);
    int lane = threadIdx.x & 63;
    float bsum = bins[code];
    if (lane == 0)
        new_cs_out[code] = cluster_size[code] * DECAY + bsum * (1.0f - DECAY);

    float en;
    if (bsum == 0.0f) {
        en = embed_n[code * D + lane];
    } else {
        float v = embed_sum[code * D + lane] / bsum;
        float ss = v * v;
        #pragma unroll
        for (int o = 32; o > 0; o >>= 1) ss += __shfl_xor(ss, o);
        en = v / fmaxf(sqrtf(ss), 1e-12f);
    }
    new_embed_out[code * D + lane] =
        embed[code * D + lane] * DECAY + en * (1.0f - DECAY);
}

// ---------------------------------------------------------------------------
extern "C" void kernel_launch(void* const* d_in, const int* in_sizes, int n_in,
                              void* d_out, int out_size, void* d_ws, size_t ws_size,
                              hipStream_t stream)
{
    const float* x            = (const float*)d_in[0];
    const float* embed        = (const float*)d_in[1];
    const float* cluster_size = (const float*)d_in[2];

    float* out     = (float*)d_out;
    float* q_out   = out;                          // N*D
    float* ind_out = out + (size_t)N * D;          // N
    float* ne_out  = ind_out + N;                  // C*D
    float* ncs_out = ne_out + (size_t)C * D;       // C

    char* ws = (char*)d_ws;
    float*          embed_n     = (float*)ws;                       // 1 MB
    float*          embed_sum   = (float*)(ws + (1u << 20));        // 1 MB
    float*          bins        = (float*)(ws + (2u << 20));        // 16 KB
    int*            dirty_list  = (int*)(ws + (2u << 20) + 65536);  // 256 KB
    int*            dirty_count = (int*)(ws + (2u << 20) + 65536 + 262144);
    unsigned short* e_hi        = (unsigned short*)(ws + 3 * (1u << 20));  // 512 KB
    unsigned short* e_lo        = (unsigned short*)(ws + 3 * (1u << 20) + 524288);

    prep_e_kernel<<<C / 4, 256, 0, stream>>>(embed, embed_n, e_hi, e_lo,
                                             embed_sum, bins, dirty_count);
    assign_mfma_kernel<<<dim3(N / 128, 2), 256, 0, stream>>>(x, e_hi, e_lo,
                                                             q_out);
    merge_scatter_kernel<<<N / 4, 256, 0, stream>>>(x, embed, q_out, ind_out,
                                                    embed_sum, bins,
                                                    dirty_count, dirty_list);
    fallback_kernel<<<1024, 256, 0, stream>>>(x, embed, embed_n, dirty_count,
                                              dirty_list, ind_out, q_out,
                                              embed_sum, bins);
    finalize_kernel<<<C / 4, 256, 0, stream>>>(embed, cluster_size, embed_n,
                                               embed_sum, bins, ne_out, ncs_out);
}

// Round 8
// 173.063 us; speedup vs baseline: 74.6789x; 1.3979x over previous
//
#include <hip/hip_runtime.h>
#include <math.h>

#define DECAY 0.8f
constexpr int B_     = 16;
constexpr int NSEQ   = 4096;
constexpr int D      = 64;
constexpr int C      = 4096;
constexpr int N      = B_ * NSEQ;       // 65536 rows
constexpr int NCHUNK = 4;               // code chunks (blockIdx.y)
constexpr int CCHUNK = C / NCHUNK;      // 1024 codes
constexpr int PANEL  = 64;              // codes per LDS panel (16 KB total)
constexpr int NPANEL = CCHUNK / PANEL;  // 16

#define GATE_THR  3e-4f                  // >> 2x mfma-split err (~1e-4 at ||x||<=12)
#define CONS_THR  1e-3f                  // consistency: exact-vs-approx winner

typedef __attribute__((ext_vector_type(8))) short bf16x8;
typedef __attribute__((ext_vector_type(4))) float f32x4;

__device__ __forceinline__ unsigned short bf16_rn(float f) {
    unsigned u = __builtin_bit_cast(unsigned, f);
    u += 0x7FFFu + ((u >> 16) & 1u);
    return (unsigned short)(u >> 16);
}
__device__ __forceinline__ float bf16_to_f(unsigned short h) {
    unsigned u = ((unsigned)h) << 16;
    return __builtin_bit_cast(float, u);
}
__device__ __forceinline__ f32x4 mfma16(bf16x8 a, bf16x8 b, f32x4 c) {
    return __builtin_amdgcn_mfma_f32_16x16x32_bf16(a, b, c, 0, 0, 0);
}

// ---------------------------------------------------------------------------
// Kernel 1: embed_n = l2norm(embed) (f32), bf16 hi/lo split in the
// XOR-swizzled LDS-image layout (granule g of code row at g^(code&7)).
// Zeroes embed_sum / bins / dirty_count.
// ---------------------------------------------------------------------------
__global__ __launch_bounds__(256) void prep_e_kernel(
    const float* __restrict__ embed,
    float* __restrict__ embed_n,
    unsigned short* __restrict__ e_hi,
    unsigned short* __restrict__ e_lo,
    float* __restrict__ embed_sum,
    float* __restrict__ bins,
    int* __restrict__ dirty_count)
{
    int code = blockIdx.x * 4 + (threadIdx.x >> 6);
    int lane = threadIdx.x & 63;
    float v = embed[code * D + lane];
    float ss = v * v;
    #pragma unroll
    for (int o = 32; o > 0; o >>= 1) ss += __shfl_xor(ss, o);
    float inv = 1.0f / fmaxf(sqrtf(ss), 1e-12f);
    float en = v * inv;
    embed_n[code * D + lane] = en;

    unsigned short hi = bf16_rn(en);
    unsigned short lo = bf16_rn(en - bf16_to_f(hi));
    int g   = lane >> 3;                               // 16B granule 0..7
    int pos = code * D + ((g ^ (code & 7)) << 3) + (lane & 7);
    e_hi[pos] = hi;
    e_lo[pos] = lo;

    embed_sum[code * D + lane] = 0.0f;
    if (lane == 0) bins[code] = 0.0f;
    if (blockIdx.x == 0 && threadIdx.x == 0) *dirty_count = 0;
}

// ---------------------------------------------------------------------------
// Kernel 2: MFMA partial argmax over a 1024-code chunk (blockIdx.y of 4).
// 2048 blocks = 8 blocks/CU, 32 waves/CU (max occupancy); LDS 16 KB/block.
// TILE-GRANULAR bookkeeping: per (tile,g) reduce the 4 acc elems to one
// quarter-tile max (codes tile*16+lg*4..+3) and top-2-track only that value
// plus the wave-uniform tile id. The exact winner-within-tile is recovered
// later by an exact fp32 rescan of the 16-code tile in merge_scatter; the
// approx value only gates cross-tile proximity (dirty -> exact fallback).
// Partial (m1, tile, m2x, 0) -> the row's quantize slot (float4 at chunk*4).
// ---------------------------------------------------------------------------
__global__ __launch_bounds__(256) void assign_mfma_kernel(
    const float* __restrict__ x,
    const unsigned short* __restrict__ e_hi,
    const unsigned short* __restrict__ e_lo,
    float* __restrict__ part)               // == q_out region of d_out
{
    __shared__ unsigned short lds_hi[PANEL * D];   // 8 KB
    __shared__ unsigned short lds_lo[PANEL * D];   // 8 KB

    const int tid  = threadIdx.x;
    const int lane = tid & 63;
    const int wid  = tid >> 6;
    const int l15  = lane & 15;
    const int lg   = lane >> 4;                  // 0..3
    const int rb   = (blockIdx.x * 4 + wid) * 32;
    const int cy   = blockIdx.y;                 // code chunk 0..3

    // ---- x fragments (2 row-groups x 2 K-chunks), bf16 hi/lo split
    bf16x8 xhi[2][2], xlo[2][2];
    #pragma unroll
    for (int g = 0; g < 2; ++g) {
        #pragma unroll
        for (int c = 0; c < 2; ++c) {
            const float* p = x + (size_t)(rb + g * 16 + l15) * D + c * 32 + lg * 8;
            float4 t0 = *(const float4*)p;
            float4 t1 = *(const float4*)(p + 4);
            float e[8] = {t0.x, t0.y, t0.z, t0.w, t1.x, t1.y, t1.z, t1.w};
            bf16x8 h, l2;
            #pragma unroll
            for (int j = 0; j < 8; ++j) {
                unsigned short hh = bf16_rn(e[j]);
                h[j]  = (short)hh;
                l2[j] = (short)bf16_rn(e[j] - bf16_to_f(hh));
            }
            xhi[g][c] = h;
            xlo[g][c] = l2;
        }
    }

    // swizzled LDS read offsets; granule index = c*4+lg, s7 = l15&7
    // (tile base t*16*D keeps (row&7) == l15&7, so s7 is tile-invariant)
    const int s7   = l15 & 7;
    const int off0 = l15 * D + (((0 + lg) ^ s7) << 3);
    const int off1 = l15 * D + (((4 + lg) ^ s7) << 3);

    float m1[2] = {-3.4e38f, -3.4e38f};
    float m2[2] = {-3.4e38f, -3.4e38f};
    int   tl[2] = {0, 0};

    for (int p = 0; p < NPANEL; ++p) {           // 16 panels of 64 codes
        const int pp = cy * NPANEL + p;          // global panel id 0..63
        __syncthreads();
        {   // linear stage: 16 KB total (512 float4 per array, 2 iters)
            const float4* gh = (const float4*)(e_hi + (size_t)pp * PANEL * D);
            const float4* gl = (const float4*)(e_lo + (size_t)pp * PANEL * D);
            float4* lh = (float4*)lds_hi;
            float4* ll = (float4*)lds_lo;
            lh[tid]       = gh[tid];
            lh[256 + tid] = gh[256 + tid];
            ll[tid]       = gl[tid];
            ll[256 + tid] = gl[256 + tid];
        }
        __syncthreads();

        #pragma unroll
        for (int t = 0; t < PANEL / 16; ++t) {   // 4 code-tiles of 16
            bf16x8 eh0 = *(const bf16x8*)(lds_hi + t * 1024 + off0);
            bf16x8 eh1 = *(const bf16x8*)(lds_hi + t * 1024 + off1);
            bf16x8 el0 = *(const bf16x8*)(lds_lo + t * 1024 + off0);
            bf16x8 el1 = *(const bf16x8*)(lds_lo + t * 1024 + off1);
            const int pt = pp * 4 + t;           // global tile id 0..255
            #pragma unroll
            for (int g = 0; g < 2; ++g) {
                f32x4 acc = {0.f, 0.f, 0.f, 0.f};
                acc = mfma16(eh0, xhi[g][0], acc);
                acc = mfma16(eh1, xhi[g][1], acc);
                acc = mfma16(el0, xhi[g][0], acc);
                acc = mfma16(el1, xhi[g][1], acc);
                acc = mfma16(eh0, xlo[g][0], acc);
                acc = mfma16(eh1, xlo[g][1], acc);
                // quarter-tile max (this lane's 4 codes of the tile)
                float t1 = fmaxf(fmaxf(acc[0], acc[1]), fmaxf(acc[2], acc[3]));
                float mn = fminf(m1[g], t1);
                bool  gt = t1 > m1[g];
                tl[g] = gt ? pt : tl[g];         // wave-uniform source
                m1[g] = fmaxf(m1[g], t1);
                m2[g] = fmaxf(m2[g], mn);
            }
        }
    }

    // ---- merge lg quarters via shuffle; m2 becomes best-outside-winner-
    // quarter; exact within-tile ordering is resolved later by the rescan.
    #pragma unroll
    for (int g = 0; g < 2; ++g) {
        float a1 = m1[g], a2 = m2[g];
        int   at = tl[g];
        #pragma unroll
        for (int d = 16; d <= 32; d <<= 1) {
            float b1 = __shfl_xor(a1, d);
            float b2 = __shfl_xor(a2, d);
            int   bt = __shfl_xor(at, d);
            float nm2 = fmaxf(fmaxf(a2, b2), fminf(a1, b1));
            bool  take = (b1 > a1);              // exact ties -> m2==m1 -> dirty
            a1 = take ? b1 : a1;
            at = take ? bt : at;
            a2 = nm2;
        }
        if (lane < 16) {
            int row = rb + g * 16 + lane;
            float4 pr;
            pr.x = a1; pr.y = (float)at; pr.z = a2; pr.w = 0.0f;
            *reinterpret_cast<float4*>(part + (size_t)row * D + cy * 4) = pr;
        }
    }
}

// ---------------------------------------------------------------------------
// Kernel 3: fused merge + exact tile rescan + scatter, one WAVE per row.
// Reads the 4 chunk partials, picks the winning tile, rescans its 16 codes
// in exact fp32 (4 lanes per code, butterfly top-2 with lower-index
// tie-break == reference first-max). Cross-tile ambiguity (w1 - m2x <= THR)
// or approx/exact inconsistency -> dirty list for the exact full fallback.
// Clean rows: write ind + gather q + EMA atomics.
// ---------------------------------------------------------------------------
__global__ __launch_bounds__(256) void merge_scatter_kernel(
    const float* __restrict__ x,
    const float* __restrict__ embed,
    const float* __restrict__ embed_n,
    float* __restrict__ q_out,               // holds partials on entry
    float* __restrict__ ind_out,
    float* __restrict__ embed_sum,
    float* __restrict__ bins,
    int* __restrict__ dirty_count,
    int* __restrict__ dirty_list)
{
    int wid  = threadIdx.x >> 6;
    int lane = threadIdx.x & 63;
    int row  = blockIdx.x * 4 + wid;

    // ---- merge the 4 chunk partials (broadcast reads)
    float w1a, m2x; int wt;
    {
        const float4* pp = reinterpret_cast<const float4*>(q_out + (size_t)row * D);
        float4 P = pp[0];
        w1a = P.x; wt = (int)P.y; m2x = P.z;
        #pragma unroll
        for (int j = 1; j < NCHUNK; ++j) {
            float4 Q = pp[j];
            float nm2 = fmaxf(fmaxf(m2x, Q.z), fminf(w1a, Q.x));
            if (Q.x > w1a) { w1a = Q.x; wt = (int)Q.y; }
            m2x = nm2;
        }
    }

    // ---- exact fp32 rescan of the 16-code winner tile
    int   csub = lane >> 2;                  // code within tile 0..15
    int   code = wt * 16 + csub;
    float dot;
    {
        const float4* ep = (const float4*)(embed_n + (size_t)code * D + (lane & 3) * 16);
        const float4* xp = (const float4*)(x + (size_t)row * D + (lane & 3) * 16);
        float a0 = 0.f, a1 = 0.f, a2 = 0.f, a3 = 0.f;
        #pragma unroll
        for (int k = 0; k < 4; ++k) {
            float4 e = ep[k], xx = xp[k];
            a0 = fmaf(e.x, xx.x, a0);
            a1 = fmaf(e.y, xx.y, a1);
            a2 = fmaf(e.z, xx.z, a2);
            a3 = fmaf(e.w, xx.w, a3);
        }
        dot = (a0 + a1) + (a2 + a3);
        dot += __shfl_xor(dot, 1);
        dot += __shfl_xor(dot, 2);           // all 4 lanes of group hold full dot
    }
    // butterfly top-2 over the 16 distinct codes (d=4..32 never meets dups)
    float v = dot, s = -3.4e38f;
    int   vi = code;
    #pragma unroll
    for (int d = 4; d <= 32; d <<= 1) {
        float bv = __shfl_xor(v, d);
        float bs = __shfl_xor(s, d);
        int   bi = __shfl_xor(vi, d);
        float ns = fmaxf(fmaxf(s, bs), fminf(v, bv));
        bool  take = (bv > v) || (bv == v && bi < vi);
        v  = take ? bv : v;
        vi = take ? bi : vi;
        s  = ns;
    }

    bool dirty = (v - m2x <= GATE_THR) || (fabsf(v - w1a) > CONS_THR);
    if (dirty) {
        if (lane == 0) {
            int slot = atomicAdd(dirty_count, 1);
            dirty_list[slot] = row;
        }
        return;
    }

    // ---- scatter (clean row)
    float xk = x[(size_t)row * D + lane];
    float ss = xk * xk;
    #pragma unroll
    for (int o = 32; o > 0; o >>= 1) ss += __shfl_xor(ss, o);
    float inv = 1.0f / fmaxf(sqrtf(ss), 1e-12f);

    if (lane == 0) {
        ind_out[row] = (float)vi;
        atomicAdd(&bins[vi], 1.0f);
    }
    q_out[(size_t)row * D + lane] = embed[(size_t)vi * D + lane];
    atomicAdd(&embed_sum[(size_t)vi * D + lane], xk * inv);
}

// ---------------------------------------------------------------------------
// Kernel 4: exact fp32 re-argmax for dirty rows + their deferred scatter.
// 1024 blocks, one block per dirty row (grid-stride); ascending scan + LDS
// tree reduce with lower-index tie-break == reference argmax.
// ---------------------------------------------------------------------------
__global__ __launch_bounds__(256) void fallback_kernel(
    const float* __restrict__ x,
    const float* __restrict__ embed,
    const float* __restrict__ embed_n,
    const int* __restrict__ dirty_count,
    const int* __restrict__ dirty_list,
    float* __restrict__ ind_out,
    float* __restrict__ q_out,
    float* __restrict__ embed_sum,
    float* __restrict__ bins)
{
    __shared__ float xs[D];
    __shared__ float bv[256];
    __shared__ int   bidx[256];
    int cnt = *dirty_count;
    for (int i = blockIdx.x; i < cnt; i += gridDim.x) {
        int row = dirty_list[i];
        __syncthreads();
        if (threadIdx.x < D) xs[threadIdx.x] = x[(size_t)row * D + threadIdx.x];
        __syncthreads();
        float best = -3.4e38f;
        int   bi   = 0;
        int   c0   = threadIdx.x * 16;
        for (int c = c0; c < c0 + 16; ++c) {
            const float4* ep = (const float4*)(embed_n + (size_t)c * D);
            const float4* xp = (const float4*)xs;
            float a0 = 0.f, a1 = 0.f, a2 = 0.f, a3 = 0.f;
            #pragma unroll
            for (int k = 0; k < D / 4; ++k) {
                float4 e = ep[k], xx = xp[k];
                a0 = fmaf(e.x, xx.x, a0);
                a1 = fmaf(e.y, xx.y, a1);
                a2 = fmaf(e.z, xx.z, a2);
                a3 = fmaf(e.w, xx.w, a3);
            }
            float dd = (a0 + a1) + (a2 + a3);
            if (dd > best) { best = dd; bi = c; }
        }
        bv[threadIdx.x]   = best;
        bidx[threadIdx.x] = bi;
        __syncthreads();
        #pragma unroll
        for (int s = 128; s > 0; s >>= 1) {
            if (threadIdx.x < s) {
                float v2 = bv[threadIdx.x + s];
                int   i2 = bidx[threadIdx.x + s];
                if (v2 > bv[threadIdx.x] ||
                    (v2 == bv[threadIdx.x] && i2 < bidx[threadIdx.x])) {
                    bv[threadIdx.x]   = v2;
                    bidx[threadIdx.x] = i2;
                }
            }
            __syncthreads();
        }
        int fi = bidx[0];
        if (threadIdx.x == 0) {
            ind_out[row] = (float)fi;
            atomicAdd(&bins[fi], 1.0f);
        }
        if (threadIdx.x < 64) {
            float xk = xs[threadIdx.x];
            float ss = xk * xk;
            #pragma unroll
            for (int o = 32; o > 0; o >>= 1) ss += __shfl_xor(ss, o);
            float inv = 1.0f / fmaxf(sqrtf(ss), 1e-12f);
            q_out[(size_t)row * D + threadIdx.x] =
                embed[(size_t)fi * D + threadIdx.x];
            atomicAdd(&embed_sum[(size_t)fi * D + threadIdx.x], xk * inv);
        }
        __syncthreads();
    }
}

// ---------------------------------------------------------------------------
// Kernel 5: EMA finalize per code. One wave per code.
// ---------------------------------------------------------------------------
__global__ __launch_bounds__(256) void finalize_kernel(
    const float* __restrict__ embed,
    const float* __restrict__ cluster_size,
    const float* __restrict__ embed_n,
    const float* __restrict__ embed_sum,
    const float* __restrict__ bins,
    float* __restrict__ new_embed_out,
    float* __restrict__ new_cs_out)
{
    int code = blockIdx.x * 4 + (threadIdx.x >> 6);
    int lane = threadIdx.x & 63;
    float bsum = bins[code];
    if (lane == 0)
        new_cs_out[code] = cluster_size[code] * DECAY + bsum * (1.0f - DECAY);

    float en;
    if (bsum == 0.0f) {
        en = embed_n[code * D + lane];
    } else {
        float v = embed_sum[code * D + lane] / bsum;
        float ss = v * v;
        #pragma unroll
        for (int o = 32; o > 0; o >>= 1) ss += __shfl_xor(ss, o);
        en = v / fmaxf(sqrtf(ss), 1e-12f);
    }
    new_embed_out[code * D + lane] =
        embed[code * D + lane] * DECAY + en * (1.0f - DECAY);
}

// ---------------------------------------------------------------------------
extern "C" void kernel_launch(void* const* d_in, const int* in_sizes, int n_in,
                              void* d_out, int out_size, void* d_ws, size_t ws_size,
                              hipStream_t stream)
{
    const float* x            = (const float*)d_in[0];
    const float* embed        = (const float*)d_in[1];
    const float* cluster_size = (const float*)d_in[2];

    float* out     = (float*)d_out;
    float* q_out   = out;                          // N*D
    float* ind_out = out + (size_t)N * D;          // N
    float* ne_out  = ind_out + N;                  // C*D
    float* ncs_out = ne_out + (size_t)C * D;       // C

    char* ws = (char*)d_ws;
    float*          embed_n     = (float*)ws;                       // 1 MB
    float*          embed_sum   = (float*)(ws + (1u << 20));        // 1 MB
    float*          bins        = (float*)(ws + (2u << 20));        // 16 KB
    int*            dirty_list  = (int*)(ws + (2u << 20) + 65536);  // 256 KB
    int*            dirty_count = (int*)(ws + (2u << 20) + 65536 + 262144);
    unsigned short* e_hi        = (unsigned short*)(ws + 3 * (1u << 20));  // 512 KB
    unsigned short* e_lo        = (unsigned short*)(ws + 3 * (1u << 20) + 524288);

    prep_e_kernel<<<C / 4, 256, 0, stream>>>(embed, embed_n, e_hi, e_lo,
                                             embed_sum, bins, dirty_count);
    assign_mfma_kernel<<<dim3(N / 128, NCHUNK), 256, 0, stream>>>(
        x, e_hi, e_lo, q_out);
    merge_scatter_kernel<<<N / 4, 256, 0, stream>>>(x, embed, embed_n,
                                                    q_out, ind_out,
                                                    embed_sum, bins,
                                                    dirty_count, dirty_list);
    fallback_kernel<<<1024, 256, 0, stream>>>(x, embed, embed_n, dirty_count,
                                              dirty_list, ind_out, q_out,
                                              embed_sum, bins);
    finalize_kernel<<<C / 4, 256, 0, stream>>>(embed, cluster_size, embed_n,
                                               embed_sum, bins, ne_out, ncs_out);
}